// Round 1
// baseline (148.228 us; speedup 1.0000x reference)
//
#include <hip/hip_runtime.h>

#define S_DIM 52
#define SS 2704           // 52*52
#define NA 5
#define NC 20
#define NB 128
#define CELLS (NB * SS)   // 346112
#define BLOCK 256
#define NBLK (CELLS / BLOCK)  // 1352 exactly

__device__ __forceinline__ float sigmoidf_(float x) {
    return 1.0f / (1.0f + __expf(-x));
}
__device__ __forceinline__ float softplusf_(float x) {
    // logaddexp(0, x) = max(x,0) + log1p(exp(-|x|))
    return fmaxf(x, 0.0f) + log1pf(__expf(-fabsf(x)));
}

// Reduce 4 per-thread partials across a 256-thread block.
// On return, thread 0 holds the block sums in a[0..3].
__device__ __forceinline__ bool block_reduce4(float v0, float v1, float v2, float v3,
                                              float a[4]) {
    #pragma unroll
    for (int off = 32; off > 0; off >>= 1) {
        v0 += __shfl_xor(v0, off, 64);
        v1 += __shfl_xor(v1, off, 64);
        v2 += __shfl_xor(v2, off, 64);
        v3 += __shfl_xor(v3, off, 64);
    }
    __shared__ float red[4][4];
    int wid = threadIdx.x >> 6, lane = threadIdx.x & 63;
    if (lane == 0) {
        red[wid][0] = v0; red[wid][1] = v1; red[wid][2] = v2; red[wid][3] = v3;
    }
    __syncthreads();
    if (threadIdx.x == 0) {
        #pragma unroll
        for (int q = 0; q < 4; ++q)
            a[q] = red[0][q] + red[1][q] + red[2][q] + red[3][q];
        return true;
    }
    return false;
}

// partial layout per block: [xywh, cls, obj, noobj]
__global__ __launch_bounds__(BLOCK) void yolo_main(
        const float* __restrict__ P,      // (B, 125, S, S)
        const float* __restrict__ T,      // (B, S, S, 5, 25)
        const float* __restrict__ anch,   // (5, 2)
        float* __restrict__ partial) {
    int cell = blockIdx.x * BLOCK + threadIdx.x;   // in [0, CELLS)
    int b  = cell / SS;
    int ij = cell - b * SS;
    const float* Pb = P + (size_t)b * 125 * SS + ij;
    const float* Tc = T + (size_t)cell * 125;

    float s_xywh = 0.0f, s_cls = 0.0f, s_obj = 0.0f, s_noobj = 0.0f;

    #pragma unroll
    for (int a = 0; a < NA; ++a) {
        const float* Pa = Pb + (size_t)(a * 25) * SS;
        const float* Ta = Tc + a * 25;
        float obj  = Ta[4];
        float conf = Pa[4 * SS];
        float cp = sigmoidf_(conf);
        if (obj != 0.0f) {
            float tx = Pa[0], ty = Pa[SS], tw = Pa[2 * SS], th = Pa[3 * SS];
            float gx = Ta[0], gy = Ta[1], gw = Ta[2], gh = Ta[3];
            float cx = sigmoidf_(tx), cy = sigmoidf_(ty);
            float pw = __expf(tw) * anch[2 * a];
            float ph = __expf(th) * anch[2 * a + 1];
            // IoU is invariant to the common (+j, +i) shift -> dropped.
            float iw = fmaxf(fminf(gx + 0.5f * gw, cx + 0.5f * pw) -
                             fmaxf(gx - 0.5f * gw, cx - 0.5f * pw), 0.0f);
            float ih = fmaxf(fminf(gy + 0.5f * gh, cy + 0.5f * ph) -
                             fmaxf(gy - 0.5f * gh, cy - 0.5f * ph), 0.0f);
            float inter = iw * ih;
            float uni = gw * gh + pw * ph - inter;
            float iou = (uni > 0.0f) ? inter / uni : 0.0f;

            float dx = cx - gx, dy = cy - gy;
            s_xywh += dx * dx + dy * dy;
            const float eps = 1e-6f;
            float dw = sqrtf(pw + eps) - sqrtf(gw + eps);
            float dh = sqrtf(ph + eps) - sqrtf(gh + eps);
            s_xywh += dw * dw + dh * dh;

            float dob = iou - cp;
            s_obj += dob * dob;

            #pragma unroll
            for (int k = 0; k < NC; ++k) {
                float l = Pa[(size_t)(5 + k) * SS];
                float t = Ta[5 + k];
                s_cls += softplusf_(l) - l * t;
            }
        } else {
            s_noobj += cp * cp;
        }
    }

    float a4[4];
    if (block_reduce4(s_xywh, s_cls, s_obj, s_noobj, a4)) {
        float* p = partial + (size_t)blockIdx.x * 4;
        p[0] = a4[0]; p[1] = a4[1]; p[2] = a4[2]; p[3] = a4[3];
    }
}

__global__ __launch_bounds__(BLOCK) void yolo_reduce(
        const float* __restrict__ partial, int n, float* __restrict__ out) {
    float v0 = 0.0f, v1 = 0.0f, v2 = 0.0f, v3 = 0.0f;
    for (int i = threadIdx.x; i < n; i += BLOCK) {
        const float* p = partial + (size_t)i * 4;
        v0 += p[0]; v1 += p[1]; v2 += p[2]; v3 += p[3];
    }
    float a4[4];
    if (block_reduce4(v0, v1, v2, v3, a4)) {
        float xywh = a4[0], cls = a4[1], obj = a4[2], noobj = a4[3];
        out[0] = 5.0f * xywh + 5.0f * obj + 0.5f * noobj + cls;
        out[1] = xywh;
        out[2] = cls;
        out[3] = obj + noobj;
    }
}

extern "C" void kernel_launch(void* const* d_in, const int* in_sizes, int n_in,
                              void* d_out, int out_size, void* d_ws, size_t ws_size,
                              hipStream_t stream) {
    const float* P = (const float*)d_in[0];
    const float* T = (const float*)d_in[1];
    const float* anch = (const float*)d_in[2];
    float* out = (float*)d_out;
    float* partial = (float*)d_ws;   // NBLK * 4 floats = 21.6 KB

    yolo_main<<<NBLK, BLOCK, 0, stream>>>(P, T, anch, partial);
    yolo_reduce<<<1, BLOCK, 0, stream>>>(partial, NBLK, out);
}

// Round 2
// 71.079 us; speedup vs baseline: 2.0854x; 2.0854x over previous
//
#include <hip/hip_runtime.h>

#define S_DIM 52
#define SS 2704              // 52*52
#define NA 5
#define NC 20
#define NB 128
#define CELLS (NB * SS)      // 346112  (multiple of 64 -> anchor is wave-uniform)
#define TOTAL (CELLS * NA)   // 1730560
#define BLOCK 256
#define NBLK (TOTAL / BLOCK) // 6760 exactly

__device__ __forceinline__ float fast_sigmoid(float x) {
    return __builtin_amdgcn_rcpf(1.0f + __expf(-x));
}
__device__ __forceinline__ float fast_softplus(float x) {
    // logaddexp(0,x) = max(x,0) + log(1 + exp(-|x|)); all HW instrs
    return fmaxf(x, 0.0f) + __logf(1.0f + __expf(-fabsf(x)));
}

// Reduce 4 per-thread partials across a 256-thread block; thread 0 gets sums.
__device__ __forceinline__ bool block_reduce4(float v0, float v1, float v2, float v3,
                                              float a[4]) {
    #pragma unroll
    for (int off = 32; off > 0; off >>= 1) {
        v0 += __shfl_xor(v0, off, 64);
        v1 += __shfl_xor(v1, off, 64);
        v2 += __shfl_xor(v2, off, 64);
        v3 += __shfl_xor(v3, off, 64);
    }
    __shared__ float red[4][4];
    int wid = threadIdx.x >> 6, lane = threadIdx.x & 63;
    if (lane == 0) {
        red[wid][0] = v0; red[wid][1] = v1; red[wid][2] = v2; red[wid][3] = v3;
    }
    __syncthreads();
    if (threadIdx.x == 0) {
        #pragma unroll
        for (int q = 0; q < 4; ++q)
            a[q] = red[0][q] + red[1][q] + red[2][q] + red[3][q];
        return true;
    }
    return false;
}

// partial layout per block: [xywh, cls, obj, noobj]
__global__ __launch_bounds__(BLOCK) void yolo_main(
        const float* __restrict__ P,      // (B, 125, S, S)
        const float* __restrict__ T,      // (B, S, S, 5, 25)
        const float* __restrict__ anch,   // (5, 2)
        float* __restrict__ partial) {
    int idx  = blockIdx.x * BLOCK + threadIdx.x;   // in [0, TOTAL)
    int a    = idx / CELLS;                        // wave-uniform (CELLS % 64 == 0)
    int cell = idx - a * CELLS;
    int b    = cell / SS;
    int ij   = cell - b * SS;

    const float* Pa = P + (size_t)b * 125 * SS + (size_t)(a * 25) * SS + ij;
    const float* Ta = T + (size_t)cell * 125 + a * 25;

    float aw = anch[2 * a];       // scalar (a uniform)
    float ah = anch[2 * a + 1];

    float s_xywh = 0.0f, s_cls = 0.0f, s_obj = 0.0f, s_noobj = 0.0f;

    float obj  = Ta[4];
    float conf = Pa[4 * SS];
    float cp   = fast_sigmoid(conf);

    if (obj != 0.0f) {
        float tx = Pa[0], ty = Pa[SS], tw = Pa[2 * SS], th = Pa[3 * SS];
        float gx = Ta[0], gy = Ta[1], gw = Ta[2], gh = Ta[3];
        float cx = fast_sigmoid(tx), cy = fast_sigmoid(ty);
        float pw = __expf(tw) * aw;
        float ph = __expf(th) * ah;
        // IoU invariant to common (+j,+i) shift -> dropped.
        float iw = fmaxf(fminf(gx + 0.5f * gw, cx + 0.5f * pw) -
                         fmaxf(gx - 0.5f * gw, cx - 0.5f * pw), 0.0f);
        float ih = fmaxf(fminf(gy + 0.5f * gh, cy + 0.5f * ph) -
                         fmaxf(gy - 0.5f * gh, cy - 0.5f * ph), 0.0f);
        float inter = iw * ih;
        float uni   = gw * gh + pw * ph - inter;
        float iou   = (uni > 0.0f) ? inter * __builtin_amdgcn_rcpf(uni) : 0.0f;

        float dx = cx - gx, dy = cy - gy;
        s_xywh = dx * dx + dy * dy;
        const float eps = 1e-6f;
        float dw = __fsqrt_rn(pw + eps) - __fsqrt_rn(gw + eps);
        float dh = __fsqrt_rn(ph + eps) - __fsqrt_rn(gh + eps);
        s_xywh += dw * dw + dh * dh;

        float dob = iou - cp;
        s_obj = dob * dob;

        #pragma unroll
        for (int k = 0; k < NC; ++k) {
            float l = Pa[(size_t)(5 + k) * SS];
            float t = Ta[5 + k];
            s_cls += fast_softplus(l) - l * t;
        }
    } else {
        s_noobj = cp * cp;
    }

    float a4[4];
    if (block_reduce4(s_xywh, s_cls, s_obj, s_noobj, a4)) {
        float* p = partial + (size_t)blockIdx.x * 4;
        p[0] = a4[0]; p[1] = a4[1]; p[2] = a4[2]; p[3] = a4[3];
    }
}

__global__ __launch_bounds__(BLOCK) void yolo_reduce(
        const float* __restrict__ partial, int n, float* __restrict__ out) {
    float v0 = 0.0f, v1 = 0.0f, v2 = 0.0f, v3 = 0.0f;
    for (int i = threadIdx.x; i < n; i += BLOCK) {
        const float* p = partial + (size_t)i * 4;
        v0 += p[0]; v1 += p[1]; v2 += p[2]; v3 += p[3];
    }
    float a4[4];
    if (block_reduce4(v0, v1, v2, v3, a4)) {
        float xywh = a4[0], cls = a4[1], obj = a4[2], noobj = a4[3];
        out[0] = 5.0f * xywh + 5.0f * obj + 0.5f * noobj + cls;
        out[1] = xywh;
        out[2] = cls;
        out[3] = obj + noobj;
    }
}

extern "C" void kernel_launch(void* const* d_in, const int* in_sizes, int n_in,
                              void* d_out, int out_size, void* d_ws, size_t ws_size,
                              hipStream_t stream) {
    const float* P = (const float*)d_in[0];
    const float* T = (const float*)d_in[1];
    const float* anch = (const float*)d_in[2];
    float* out = (float*)d_out;
    float* partial = (float*)d_ws;   // NBLK * 4 floats = 108 KB

    yolo_main<<<NBLK, BLOCK, 0, stream>>>(P, T, anch, partial);
    yolo_reduce<<<1, BLOCK, 0, stream>>>(partial, NBLK, out);
}

// Round 3
// 68.984 us; speedup vs baseline: 2.1487x; 1.0304x over previous
//
#include <hip/hip_runtime.h>

#define S_DIM 52
#define SS 2704              // 52*52
#define NA 5
#define NC 20
#define NB 128
#define CELLS (NB * SS)      // 346112
#define BLOCK 256
#define NBLK (CELLS / BLOCK) // 1352 exactly

__device__ __forceinline__ float fast_sigmoid(float x) {
    return __builtin_amdgcn_rcpf(1.0f + __expf(-x));
}
__device__ __forceinline__ float fast_softplus(float x) {
    // logaddexp(0,x) = max(x,0) + log(1 + exp(-|x|)); all HW instrs
    return fmaxf(x, 0.0f) + __logf(1.0f + __expf(-fabsf(x)));
}

// Reduce 4 per-thread partials across a 256-thread block; thread 0 gets sums.
__device__ __forceinline__ bool block_reduce4(float v0, float v1, float v2, float v3,
                                              float a[4]) {
    #pragma unroll
    for (int off = 32; off > 0; off >>= 1) {
        v0 += __shfl_xor(v0, off, 64);
        v1 += __shfl_xor(v1, off, 64);
        v2 += __shfl_xor(v2, off, 64);
        v3 += __shfl_xor(v3, off, 64);
    }
    __shared__ float red[4][4];
    int wid = threadIdx.x >> 6, lane = threadIdx.x & 63;
    if (lane == 0) {
        red[wid][0] = v0; red[wid][1] = v1; red[wid][2] = v2; red[wid][3] = v3;
    }
    __syncthreads();
    if (threadIdx.x == 0) {
        #pragma unroll
        for (int q = 0; q < 4; ++q)
            a[q] = red[0][q] + red[1][q] + red[2][q] + red[3][q];
        return true;
    }
    return false;
}

// One thread per CELL; all 5 anchors handled in-thread so each T line is
// touched exactly once (kills the 5x L3 re-stream of the anchor-outer map).
__global__ __launch_bounds__(BLOCK) void yolo_main(
        const float* __restrict__ P,      // (B, 125, S, S)
        const float* __restrict__ T,      // (B, S, S, 5, 25)
        const float* __restrict__ anch,   // (5, 2)
        float* __restrict__ partial) {
    int cell = blockIdx.x * BLOCK + threadIdx.x;   // [0, CELLS)
    int b  = cell / SS;
    int ij = cell - b * SS;
    const float* Pb = P + (size_t)b * 125 * SS + ij;   // coalesced plane base
    const float* Tc = T + (size_t)cell * 125;          // this cell's 500B record

    // Phase 1: issue ALL flag + conf loads unconditionally (one round trip,
    // no flag->body dependency). Flags: 5 scattered loads, lines L1-resident
    // afterwards. Conf: 5 perfectly coalesced plane loads.
    float fl[NA], cf[NA];
    #pragma unroll
    for (int a = 0; a < NA; ++a) fl[a] = Tc[a * 25 + 4];
    #pragma unroll
    for (int a = 0; a < NA; ++a) cf[a] = Pb[(size_t)(a * 25 + 4) * SS];

    float s_xywh = 0.0f, s_cls = 0.0f, s_obj = 0.0f, s_noobj = 0.0f;

    #pragma unroll
    for (int a = 0; a < NA; ++a) {
        float cp = fast_sigmoid(cf[a]);
        if (fl[a] != 0.0f) {
            const float* Pa = Pb + (size_t)(a * 25) * SS;
            const float* Ta = Tc + a * 25;             // L1-hit (line from flag load)
            float aw = anch[2 * a], ahv = anch[2 * a + 1];

            float tx = Pa[0], ty = Pa[SS], tw = Pa[2 * SS], th = Pa[3 * SS];
            float gx = Ta[0], gy = Ta[1], gw = Ta[2], gh = Ta[3];
            float cx = fast_sigmoid(tx), cy = fast_sigmoid(ty);
            float pw = __expf(tw) * aw;
            float ph = __expf(th) * ahv;
            // IoU invariant to common (+j,+i) shift -> dropped.
            float iw = fmaxf(fminf(gx + 0.5f * gw, cx + 0.5f * pw) -
                             fmaxf(gx - 0.5f * gw, cx - 0.5f * pw), 0.0f);
            float ih = fmaxf(fminf(gy + 0.5f * gh, cy + 0.5f * ph) -
                             fmaxf(gy - 0.5f * gh, cy - 0.5f * ph), 0.0f);
            float inter = iw * ih;
            float uni   = gw * gh + pw * ph - inter;
            float iou   = (uni > 0.0f) ? inter * __builtin_amdgcn_rcpf(uni) : 0.0f;

            float dx = cx - gx, dy = cy - gy;
            s_xywh += dx * dx + dy * dy;
            const float eps = 1e-6f;
            float dw = __fsqrt_rn(pw + eps) - __fsqrt_rn(gw + eps);
            float dh = __fsqrt_rn(ph + eps) - __fsqrt_rn(gh + eps);
            s_xywh += dw * dw + dh * dh;

            float dob = iou - cp;
            s_obj += dob * dob;

            #pragma unroll
            for (int k = 0; k < NC; ++k) {
                float l = Pa[(size_t)(5 + k) * SS];
                float t = Ta[5 + k];
                s_cls += fast_softplus(l) - l * t;
            }
        } else {
            s_noobj += cp * cp;
        }
    }

    float a4[4];
    if (block_reduce4(s_xywh, s_cls, s_obj, s_noobj, a4)) {
        float* p = partial + (size_t)blockIdx.x * 4;
        p[0] = a4[0]; p[1] = a4[1]; p[2] = a4[2]; p[3] = a4[3];
    }
}

__global__ __launch_bounds__(BLOCK) void yolo_reduce(
        const float* __restrict__ partial, int n, float* __restrict__ out) {
    float v0 = 0.0f, v1 = 0.0f, v2 = 0.0f, v3 = 0.0f;
    for (int i = threadIdx.x; i < n; i += BLOCK) {
        const float* p = partial + (size_t)i * 4;
        v0 += p[0]; v1 += p[1]; v2 += p[2]; v3 += p[3];
    }
    float a4[4];
    if (block_reduce4(v0, v1, v2, v3, a4)) {
        float xywh = a4[0], cls = a4[1], obj = a4[2], noobj = a4[3];
        out[0] = 5.0f * xywh + 5.0f * obj + 0.5f * noobj + cls;
        out[1] = xywh;
        out[2] = cls;
        out[3] = obj + noobj;
    }
}

extern "C" void kernel_launch(void* const* d_in, const int* in_sizes, int n_in,
                              void* d_out, int out_size, void* d_ws, size_t ws_size,
                              hipStream_t stream) {
    const float* P = (const float*)d_in[0];
    const float* T = (const float*)d_in[1];
    const float* anch = (const float*)d_in[2];
    float* out = (float*)d_out;
    float* partial = (float*)d_ws;   // NBLK * 4 floats = 21.6 KB

    yolo_main<<<NBLK, BLOCK, 0, stream>>>(P, T, anch, partial);
    yolo_reduce<<<1, BLOCK, 0, stream>>>(partial, NBLK, out);
}

// Round 4
// 65.581 us; speedup vs baseline: 2.2602x; 1.0519x over previous
//
#include <hip/hip_runtime.h>

#define SS 2704                // 52*52
#define NA 5
#define NC 20
#define NB 128
#define CELLS (NB * SS)        // 346112
#define TILE 64                // cells per block tile
#define TPB 320                // 5 waves; wave index == anchor index
#define NTILE (CELLS / TILE)   // 5408 exactly
#define TILE_F (TILE * 125)    // 8000 floats = 32 KB
#define TILE_V4 (TILE_F / 4)   // 2000 float4
#define RBLOCK 256

__device__ __forceinline__ float fast_sigmoid(float x) {
    return __builtin_amdgcn_rcpf(1.0f + __expf(-x));
}
__device__ __forceinline__ float fast_softplus(float x) {
    // logaddexp(0,x) = max(x,0) + log(1 + exp(-|x|)); all HW instrs
    return fmaxf(x, 0.0f) + __logf(1.0f + __expf(-fabsf(x)));
}

// partial layout per block: [xywh, cls, obj, noobj]
__global__ __launch_bounds__(TPB) void yolo_main(
        const float* __restrict__ P,      // (B, 125, S, S)
        const float* __restrict__ T,      // (B, S, S, 5, 25)
        const float* __restrict__ anch,   // (5, 2)
        float* __restrict__ partial) {
    __shared__ float lds[TILE_F];
    __shared__ float red[NA][4];

    int tile = blockIdx.x;

    // ---- Stage this tile's T slab (32 KB, contiguous) into LDS, coalesced ----
    const float4* src = (const float4*)(T + (size_t)tile * TILE_F);
    float4* dst = (float4*)lds;
    #pragma unroll
    for (int i = 0; i < 7; ++i) {
        int idx = threadIdx.x + i * TPB;          // 7*320 = 2240 >= 2000
        if (idx < TILE_V4) dst[idx] = src[idx];
    }
    __syncthreads();

    // ---- wave = anchor, lane = cell-in-tile ----
    int a    = threadIdx.x >> 6;                  // 0..4, wave-uniform
    int lane = threadIdx.x & 63;
    int cell = tile * TILE + lane;
    int b    = cell / SS;
    int ij   = cell - b * SS;

    const float* Pa = P + ((size_t)b * 125 + a * 25) * SS + ij;  // plane base
    const float* Tl = lds + lane * 125 + a * 25;  // stride 125 -> bank-bijective
    float aw  = anch[2 * a];
    float ahv = anch[2 * a + 1];

    float fl = Tl[4];
    float cp = fast_sigmoid(Pa[4 * SS]);          // coalesced 64-float span

    float s_xywh = 0.0f, s_cls = 0.0f, s_obj = 0.0f, s_noobj = 0.0f;

    if (fl != 0.0f) {
        float tx = Pa[0], ty = Pa[SS], tw = Pa[2 * SS], th = Pa[3 * SS];
        float gx = Tl[0], gy = Tl[1], gw = Tl[2], gh = Tl[3];
        float cx = fast_sigmoid(tx), cy = fast_sigmoid(ty);
        float pw = __expf(tw) * aw;
        float ph = __expf(th) * ahv;
        // IoU invariant to common (+j,+i) shift -> dropped.
        float iw = fmaxf(fminf(gx + 0.5f * gw, cx + 0.5f * pw) -
                         fmaxf(gx - 0.5f * gw, cx - 0.5f * pw), 0.0f);
        float ih = fmaxf(fminf(gy + 0.5f * gh, cy + 0.5f * ph) -
                         fmaxf(gy - 0.5f * gh, cy - 0.5f * ph), 0.0f);
        float inter = iw * ih;
        float uni   = gw * gh + pw * ph - inter;
        float iou   = (uni > 0.0f) ? inter * __builtin_amdgcn_rcpf(uni) : 0.0f;

        float dx = cx - gx, dy = cy - gy;
        s_xywh += dx * dx + dy * dy;
        const float eps = 1e-6f;
        float dw = __fsqrt_rn(pw + eps) - __fsqrt_rn(gw + eps);
        float dh = __fsqrt_rn(ph + eps) - __fsqrt_rn(gh + eps);
        s_xywh += dw * dw + dh * dh;

        float dob = iou - cp;
        s_obj += dob * dob;

        #pragma unroll
        for (int k = 0; k < NC; ++k) {
            float l = Pa[(size_t)(5 + k) * SS];   // contiguous span, 1-2 lines
            float t = Tl[5 + k];                  // LDS, conflict-free
            s_cls += fast_softplus(l) - l * t;
        }
    } else {
        s_noobj = cp * cp;
    }

    // ---- wave reduce (64 lanes) ----
    #pragma unroll
    for (int off = 32; off > 0; off >>= 1) {
        s_xywh  += __shfl_xor(s_xywh,  off, 64);
        s_cls   += __shfl_xor(s_cls,   off, 64);
        s_obj   += __shfl_xor(s_obj,   off, 64);
        s_noobj += __shfl_xor(s_noobj, off, 64);
    }
    if (lane == 0) {
        red[a][0] = s_xywh; red[a][1] = s_cls; red[a][2] = s_obj; red[a][3] = s_noobj;
    }
    __syncthreads();
    if (threadIdx.x == 0) {
        float r0 = 0, r1 = 0, r2 = 0, r3 = 0;
        #pragma unroll
        for (int w = 0; w < NA; ++w) {
            r0 += red[w][0]; r1 += red[w][1]; r2 += red[w][2]; r3 += red[w][3];
        }
        float* p = partial + (size_t)blockIdx.x * 4;
        p[0] = r0; p[1] = r1; p[2] = r2; p[3] = r3;
    }
}

__global__ __launch_bounds__(RBLOCK) void yolo_reduce(
        const float* __restrict__ partial, int n, float* __restrict__ out) {
    float v0 = 0.0f, v1 = 0.0f, v2 = 0.0f, v3 = 0.0f;
    for (int i = threadIdx.x; i < n; i += RBLOCK) {
        const float* p = partial + (size_t)i * 4;
        v0 += p[0]; v1 += p[1]; v2 += p[2]; v3 += p[3];
    }
    #pragma unroll
    for (int off = 32; off > 0; off >>= 1) {
        v0 += __shfl_xor(v0, off, 64);
        v1 += __shfl_xor(v1, off, 64);
        v2 += __shfl_xor(v2, off, 64);
        v3 += __shfl_xor(v3, off, 64);
    }
    __shared__ float red[4][4];
    int wid = threadIdx.x >> 6, lane = threadIdx.x & 63;
    if (lane == 0) {
        red[wid][0] = v0; red[wid][1] = v1; red[wid][2] = v2; red[wid][3] = v3;
    }
    __syncthreads();
    if (threadIdx.x == 0) {
        float xywh = 0, cls = 0, obj = 0, noobj = 0;
        #pragma unroll
        for (int q = 0; q < 4; ++q) {
            xywh += red[q][0]; cls += red[q][1]; obj += red[q][2]; noobj += red[q][3];
        }
        out[0] = 5.0f * xywh + 5.0f * obj + 0.5f * noobj + cls;
        out[1] = xywh;
        out[2] = cls;
        out[3] = obj + noobj;
    }
}

extern "C" void kernel_launch(void* const* d_in, const int* in_sizes, int n_in,
                              void* d_out, int out_size, void* d_ws, size_t ws_size,
                              hipStream_t stream) {
    const float* P = (const float*)d_in[0];
    const float* T = (const float*)d_in[1];
    const float* anch = (const float*)d_in[2];
    float* out = (float*)d_out;
    float* partial = (float*)d_ws;   // NTILE * 4 floats = 86.5 KB

    yolo_main<<<NTILE, TPB, 0, stream>>>(P, T, anch, partial);
    yolo_reduce<<<1, RBLOCK, 0, stream>>>(partial, NTILE, out);
}